// Round 10
// baseline (93.068 us; speedup 1.0000x reference)
//
#include <hip/hip_runtime.h>

// RoiPooling (crop_and_resize, bilinear): x (1,128,128,256) f32 NHWC,
// rois (4000,4) f32 [y1,x1,y2,x2] in [0,1] -> out (4000,7,7,256) f32.
//
// R10: (y0, x0>>2) sort (4096 buckets) + flat-partition pool.
// R9 (row sort) left x random within a row: block's 8 cells hit ~32
// random 1KB segments of a 256KB window -> L2-served, L1 useless.
// 4096-bucket key makes consecutive cells share a ~2-row x 5-px (~10KB)
// window -> L1-resident gathers. Sort stays cheap (R8's mistake avoided):
// 32 blocks, 16KB LDS hist, merge = 32 atomics per padded counter line.
// Scatter pass B re-ranks via LDS atomics (any within-bucket permutation
// is valid; counts match pass A -> bijective), avoiding rank caches.

typedef float v4f __attribute__((ext_vector_type(4)));

constexpr int H = 128, W = 128, C = 256;
constexpr int PH = 7, PW = 7;
constexpr int NROI = 4000;
constexpr int NCELL = NROI * PH * PW;            // 196000
constexpr int NB = 128 * 32;                     // 4096 buckets
constexpr int CSTRIDE = 16;                      // ints; 64B per counter
constexpr int BIN_BLOCKS = 32;
constexpr int CPB = NCELL / BIN_BLOCKS;          // 6125 exactly
constexpr int NXCD = 8;
constexpr int M = NCELL / NXCD;                  // 24500 cells per XCD
constexpr int GROUPS = 256;                      // blocks per XCD
constexpr int P2_BLOCKS = NXCD * GROUPS;         // 2048
constexpr size_t WS_CNT  = (size_t)NB * CSTRIDE; // 65536 ints
constexpr size_t WS_INTS = 2 * WS_CNT + (NB + 1) + NCELL;

__global__ __launch_bounds__(256) void zero_counts(int* p) {
    const int n = (int)(2 * WS_CNT);
    const int i = blockIdx.x * 256 + threadIdx.x;
    for (int j = i; j < n; j += 64 * 256) p[j] = 0;
}

__device__ __forceinline__ int cell_bucket(const float* __restrict__ rois, int cell) {
    const int r  = cell / (PH * PW);
    const int pq = cell - r * (PH * PW);
    const int iy = pq / PW;
    const int ix = pq - iy * PW;
    const float y1 = rois[r * 4 + 0];
    const float x1 = rois[r * 4 + 1];
    const float y2 = rois[r * 4 + 2];
    const float x2 = rois[r * 4 + 3];
    const float ys = y1 * (float)(H - 1) + (float)iy * ((y2 - y1) * (float)(H - 1) / (float)(PH - 1));
    const float xs = x1 * (float)(W - 1) + (float)ix * ((x2 - x1) * (float)(W - 1) / (float)(PW - 1));
    int y0 = (int)floorf(ys); y0 = min(max(y0, 0), H - 1);
    int x0 = (int)floorf(xs); x0 = min(max(x0, 0), W - 1);
    return (y0 << 5) | (x0 >> 2);
}

__global__ __launch_bounds__(256) void hist_cells(const float* __restrict__ rois,
                                                  int* __restrict__ cnt)
{
    __shared__ int lh[NB];                       // 16KB
    for (int i = threadIdx.x; i < NB; i += 256) lh[i] = 0;
    __syncthreads();
    const int c0 = blockIdx.x * CPB;
    const int c1 = c0 + CPB;
    for (int cell = c0 + threadIdx.x; cell < c1; cell += 256)
        atomicAdd(&lh[cell_bucket(rois, cell)], 1);
    __syncthreads();
    for (int i = threadIdx.x; i < NB; i += 256) {
        const int n = lh[i];
        if (n) atomicAdd(&cnt[i * CSTRIDE], n);
    }
}

__global__ __launch_bounds__(1024) void prefix_sum(const int* __restrict__ cnt,
                                                   int* __restrict__ P)
{
    __shared__ int tsum[1024];
    const int t = threadIdx.x;
    int vals[4];
    int s = 0;
#pragma unroll
    for (int i = 0; i < 4; ++i) { vals[i] = cnt[(t * 4 + i) * CSTRIDE]; s += vals[i]; }
    tsum[t] = s;
    __syncthreads();
    for (int off = 1; off < 1024; off <<= 1) {
        const int v = (t >= off) ? tsum[t - off] : 0;
        __syncthreads();
        tsum[t] += v;
        __syncthreads();
    }
    int base = (t == 0) ? 0 : tsum[t - 1];
#pragma unroll
    for (int i = 0; i < 4; ++i) { P[t * 4 + i] = base; base += vals[i]; }
    if (t == 1023) P[NB] = base;
}

__global__ __launch_bounds__(256) void scatter_cells(const float* __restrict__ rois,
                                                     const int* __restrict__ P,
                                                     int* __restrict__ head,
                                                     int* __restrict__ list)
{
    __shared__ int lcnt[NB];                     // 16KB
    __shared__ int gbase[NB];                    // 16KB
    for (int i = threadIdx.x; i < NB; i += 256) lcnt[i] = 0;
    __syncthreads();
    const int c0 = blockIdx.x * CPB;
    const int c1 = c0 + CPB;
    // Pass A: per-block bucket counts.
    for (int cell = c0 + threadIdx.x; cell < c1; cell += 256)
        atomicAdd(&lcnt[cell_bucket(rois, cell)], 1);
    __syncthreads();
    // Merge: claim global ranges (32 serialized adds per padded line).
    for (int i = threadIdx.x; i < NB; i += 256) {
        const int n = lcnt[i];
        gbase[i] = n ? P[i] + atomicAdd(&head[i * CSTRIDE], n) : 0;
    }
    __syncthreads();
    for (int i = threadIdx.x; i < NB; i += 256) lcnt[i] = 0;
    __syncthreads();
    // Pass B: re-rank (any within-bucket order is a valid sort).
    for (int cell = c0 + threadIdx.x; cell < c1; cell += 256) {
        const int b = cell_bucket(rois, cell);
        const int rank = atomicAdd(&lcnt[b], 1);
        list[gbase[b] + rank] = cell;
    }
}

__device__ __forceinline__ void cell_geom(const float* __restrict__ rois, int cell,
                                          unsigned& b00, unsigned& b01,
                                          unsigned& b10, unsigned& b11,
                                          float& wy, float& wx, bool& valid)
{
    const int r  = cell / (PH * PW);
    const int pq = cell - r * (PH * PW);
    const int iy = pq / PW;
    const int ix = pq - iy * PW;

    const float y1 = rois[r * 4 + 0];
    const float x1 = rois[r * 4 + 1];
    const float y2 = rois[r * 4 + 2];
    const float x2 = rois[r * 4 + 3];

    // Match reference order exactly.
    const float ys = y1 * (float)(H - 1) + (float)iy * ((y2 - y1) * (float)(H - 1) / (float)(PH - 1));
    const float xs = x1 * (float)(W - 1) + (float)ix * ((x2 - x1) * (float)(W - 1) / (float)(PW - 1));

    const float y0f = floorf(ys);
    const float x0f = floorf(xs);
    wy = ys - y0f;
    wx = xs - x0f;

    int y0  = (int)y0f; y0  = min(max(y0, 0), H - 1);
    int y1i = min(y0 + 1, H - 1);
    int x0  = (int)x0f; x0  = min(max(x0, 0), W - 1);
    int x1i = min(x0 + 1, W - 1);

    valid = (ys >= 0.0f) & (ys <= (float)(H - 1)) &
            (xs >= 0.0f) & (xs <= (float)(W - 1));

    b00 = ((unsigned)(y0  * W + x0 )) * C;
    b01 = ((unsigned)(y0  * W + x1i)) * C;
    b10 = ((unsigned)(y1i * W + x0 )) * C;
    b11 = ((unsigned)(y1i * W + x1i)) * C;
}

__global__ __launch_bounds__(256) void roi_pool_flat(
    const float* __restrict__ x, const float* __restrict__ rois,
    float* __restrict__ out, const int* __restrict__ list)
{
    const int xcd = blockIdx.x & (NXCD - 1);   // heuristic: == XCD id
    const int grp = blockIdx.x >> 3;
    const int wave = threadIdx.x >> 6;
    const int lane = threadIdx.x & 63;
    const unsigned c4 = (unsigned)lane * 4u;
    const int gbase = xcd * M;

    for (int c = grp; c * 8 < M; c += GROUPS) {
        const int local0 = c * 8 + wave * 2;
        int cells[2]; bool live[2], validv[2];
        float wxv[2], wyv[2];
        v4f a[2], b[2], cc[2], d[2];
#pragma unroll
        for (int k = 0; k < 2; ++k) {
            const int local = local0 + k;
            live[k] = (local < M);
            const int g = gbase + min(local, M - 1);
            const int cell = list[g];
            cells[k] = cell;
            unsigned b00, b01, b10, b11;
            cell_geom(rois, cell, b00, b01, b10, b11, wyv[k], wxv[k], validv[k]);
            if (live[k]) {
                a[k]  = *(const v4f*)(x + b00 + c4);
                b[k]  = *(const v4f*)(x + b01 + c4);
                cc[k] = *(const v4f*)(x + b10 + c4);
                d[k]  = *(const v4f*)(x + b11 + c4);
            }
        }
#pragma unroll
        for (int k = 0; k < 2; ++k) {
            if (!live[k]) continue;
            const float wx = wxv[k], wy = wyv[k];
            const v4f top = a[k]  * (1.0f - wx) + b[k] * wx;
            const v4f bot = cc[k] * (1.0f - wx) + d[k] * wx;
            v4f res = top * (1.0f - wy) + bot * wy;
            if (!validv[k]) res = (v4f)0.0f;
            v4f* o = (v4f*)(out + (unsigned)cells[k] * C + c4);
            __builtin_nontemporal_store(res, o);
        }
    }
}

// Fallback (ws too small): direct kernel.
__global__ __launch_bounds__(256) void roi_pool_plain(
    const float* __restrict__ x, const float* __restrict__ rois,
    float* __restrict__ out)
{
    const int wave = threadIdx.x >> 6;
    const int lane = threadIdx.x & 63;
    const int cell0 = (blockIdx.x * 4 + wave) * 2;
    const unsigned c4 = (unsigned)lane * 4u;

    v4f a[2], b[2], c[2], d[2];
    float wxv[2], wyv[2]; bool validv[2];
#pragma unroll
    for (int k = 0; k < 2; ++k) {
        unsigned b00, b01, b10, b11;
        cell_geom(rois, cell0 + k, b00, b01, b10, b11, wyv[k], wxv[k], validv[k]);
        a[k] = *(const v4f*)(x + b00 + c4);
        b[k] = *(const v4f*)(x + b01 + c4);
        c[k] = *(const v4f*)(x + b10 + c4);
        d[k] = *(const v4f*)(x + b11 + c4);
    }
#pragma unroll
    for (int k = 0; k < 2; ++k) {
        const float wx = wxv[k], wy = wyv[k];
        const v4f top = a[k] * (1.0f - wx) + b[k] * wx;
        const v4f bot = c[k] * (1.0f - wx) + d[k] * wx;
        v4f res = top * (1.0f - wy) + bot * wy;
        if (!validv[k]) res = (v4f)0.0f;
        v4f* o = (v4f*)(out + (unsigned)(cell0 + k) * C + c4);
        __builtin_nontemporal_store(res, o);
    }
}

extern "C" void kernel_launch(void* const* d_in, const int* in_sizes, int n_in,
                              void* d_out, int out_size, void* d_ws, size_t ws_size,
                              hipStream_t stream)
{
    const float* x    = (const float*)d_in[0];
    const float* rois = (const float*)d_in[1];
    float* out = (float*)d_out;

    if (ws_size >= WS_INTS * sizeof(int)) {
        int* cnt  = (int*)d_ws;
        int* head = cnt + WS_CNT;
        int* P    = head + WS_CNT;
        int* list = P + (NB + 1);
        zero_counts<<<64, 256, 0, stream>>>(cnt);
        hist_cells<<<BIN_BLOCKS, 256, 0, stream>>>(rois, cnt);
        prefix_sum<<<1, 1024, 0, stream>>>(cnt, P);
        scatter_cells<<<BIN_BLOCKS, 256, 0, stream>>>(rois, P, head, list);
        roi_pool_flat<<<P2_BLOCKS, 256, 0, stream>>>(x, rois, out, list);
    } else {
        roi_pool_plain<<<NCELL / 8, 256, 0, stream>>>(x, rois, out);
    }
}

// Round 11
// 73.033 us; speedup vs baseline: 1.2743x; 1.2743x over previous
//
#include <hip/hip_runtime.h>

// RoiPooling (crop_and_resize, bilinear): x (1,128,128,256) f32 NHWC,
// rois (4000,4) f32 [y1,x1,y2,x2] in [0,1] -> out (4000,7,7,256) f32.
//
// R11: (y0, x0>>4) sort -> 1024 buckets (row x 8 x-groups), at R9's exact
// sort cost structure (128 blocks, 4KB LDS hist, padded 64B counters,
// ~99 merge atomics per line across 1024 independent lines). Pool pass
// identical to R9. Concurrent per-block window shrinks 256KB -> ~40KB
// (2 rows x ~20px) -> L2 streams sequentially, partial L1 reuse.

typedef float v4f __attribute__((ext_vector_type(4)));

constexpr int H = 128, W = 128, C = 256;
constexpr int PH = 7, PW = 7;
constexpr int NROI = 4000;
constexpr int NCELL = NROI * PH * PW;            // 196000
constexpr int NB = 128 * 8;                      // 1024 buckets
constexpr int CSTRIDE = 16;                      // ints; 64B per counter
constexpr int BIN_BLOCKS = 128;
constexpr int CPB = (NCELL + BIN_BLOCKS - 1) / BIN_BLOCKS;  // 1532
constexpr int NXCD = 8;
constexpr int M = NCELL / NXCD;                  // 24500 cells per XCD
constexpr int GROUPS = 256;                      // blocks per XCD
constexpr int P2_BLOCKS = NXCD * GROUPS;         // 2048
constexpr size_t WS_CNT  = (size_t)NB * CSTRIDE; // 16384 ints
constexpr size_t WS_INTS = 2 * WS_CNT + (NB + 1) + NCELL;

__global__ __launch_bounds__(256) void zero_counts(int* p) {
    const int n = (int)(2 * WS_CNT);             // cnt + head
    const int i = blockIdx.x * 256 + threadIdx.x;
    for (int j = i; j < n; j += 32 * 256) p[j] = 0;
}

__device__ __forceinline__ int cell_bucket(const float* __restrict__ rois, int cell) {
    const int r  = cell / (PH * PW);
    const int pq = cell - r * (PH * PW);
    const int iy = pq / PW;
    const int ix = pq - iy * PW;
    const float y1 = rois[r * 4 + 0];
    const float x1 = rois[r * 4 + 1];
    const float y2 = rois[r * 4 + 2];
    const float x2 = rois[r * 4 + 3];
    const float ys = y1 * (float)(H - 1) + (float)iy * ((y2 - y1) * (float)(H - 1) / (float)(PH - 1));
    const float xs = x1 * (float)(W - 1) + (float)ix * ((x2 - x1) * (float)(W - 1) / (float)(PW - 1));
    int y0 = (int)floorf(ys); y0 = min(max(y0, 0), H - 1);
    int x0 = (int)floorf(xs); x0 = min(max(x0, 0), W - 1);
    return (y0 << 3) | (x0 >> 4);
}

__global__ __launch_bounds__(256) void hist_cells(const float* __restrict__ rois,
                                                  int* __restrict__ cnt)
{
    __shared__ int lh[NB];                       // 4KB
    for (int i = threadIdx.x; i < NB; i += 256) lh[i] = 0;
    __syncthreads();
    const int c0 = blockIdx.x * CPB;
    const int c1 = min(c0 + CPB, NCELL);
    for (int cell = c0 + threadIdx.x; cell < c1; cell += 256)
        atomicAdd(&lh[cell_bucket(rois, cell)], 1);
    __syncthreads();
    for (int i = threadIdx.x; i < NB; i += 256) {
        const int n = lh[i];
        if (n) atomicAdd(&cnt[i * CSTRIDE], n);
    }
}

__global__ __launch_bounds__(1024) void prefix_sum(const int* __restrict__ cnt,
                                                   int* __restrict__ P)
{
    __shared__ int s[NB];
    const int t = threadIdx.x;
    s[t] = cnt[t * CSTRIDE];
    __syncthreads();
    for (int off = 1; off < NB; off <<= 1) {
        const int v = (t >= off) ? s[t - off] : 0;
        __syncthreads();
        s[t] += v;
        __syncthreads();
    }
    P[t + 1] = s[t];
    if (t == 0) P[0] = 0;
}

__global__ __launch_bounds__(256) void scatter_cells(const float* __restrict__ rois,
                                                     const int* __restrict__ P,
                                                     int* __restrict__ head,
                                                     int* __restrict__ list)
{
    __shared__ int lcnt[NB];
    __shared__ int gbase[NB];
    for (int i = threadIdx.x; i < NB; i += 256) lcnt[i] = 0;
    __syncthreads();
    const int c0 = blockIdx.x * CPB;
    const int c1 = min(c0 + CPB, NCELL);
    int myb[6], myr[6];
    {
        int j = 0;
        for (int cell = c0 + threadIdx.x; cell < c1; cell += 256, ++j) {
            const int b = cell_bucket(rois, cell);
            myb[j] = b;
            myr[j] = atomicAdd(&lcnt[b], 1);
        }
    }
    __syncthreads();
    for (int i = threadIdx.x; i < NB; i += 256) {
        const int n = lcnt[i];
        gbase[i] = n ? P[i] + atomicAdd(&head[i * CSTRIDE], n) : 0;
    }
    __syncthreads();
    {
        int j = 0;
        for (int cell = c0 + threadIdx.x; cell < c1; cell += 256, ++j)
            list[gbase[myb[j]] + myr[j]] = cell;
    }
}

__device__ __forceinline__ void cell_geom(const float* __restrict__ rois, int cell,
                                          unsigned& b00, unsigned& b01,
                                          unsigned& b10, unsigned& b11,
                                          float& wy, float& wx, bool& valid)
{
    const int r  = cell / (PH * PW);
    const int pq = cell - r * (PH * PW);
    const int iy = pq / PW;
    const int ix = pq - iy * PW;

    const float y1 = rois[r * 4 + 0];
    const float x1 = rois[r * 4 + 1];
    const float y2 = rois[r * 4 + 2];
    const float x2 = rois[r * 4 + 3];

    // Match reference order exactly.
    const float ys = y1 * (float)(H - 1) + (float)iy * ((y2 - y1) * (float)(H - 1) / (float)(PH - 1));
    const float xs = x1 * (float)(W - 1) + (float)ix * ((x2 - x1) * (float)(W - 1) / (float)(PW - 1));

    const float y0f = floorf(ys);
    const float x0f = floorf(xs);
    wy = ys - y0f;
    wx = xs - x0f;

    int y0  = (int)y0f; y0  = min(max(y0, 0), H - 1);
    int y1i = min(y0 + 1, H - 1);
    int x0  = (int)x0f; x0  = min(max(x0, 0), W - 1);
    int x1i = min(x0 + 1, W - 1);

    valid = (ys >= 0.0f) & (ys <= (float)(H - 1)) &
            (xs >= 0.0f) & (xs <= (float)(W - 1));

    b00 = ((unsigned)(y0  * W + x0 )) * C;
    b01 = ((unsigned)(y0  * W + x1i)) * C;
    b10 = ((unsigned)(y1i * W + x0 )) * C;
    b11 = ((unsigned)(y1i * W + x1i)) * C;
}

__global__ __launch_bounds__(256) void roi_pool_flat(
    const float* __restrict__ x, const float* __restrict__ rois,
    float* __restrict__ out, const int* __restrict__ list)
{
    const int xcd = blockIdx.x & (NXCD - 1);   // heuristic: == XCD id
    const int grp = blockIdx.x >> 3;
    const int wave = threadIdx.x >> 6;
    const int lane = threadIdx.x & 63;
    const unsigned c4 = (unsigned)lane * 4u;
    const int gbase = xcd * M;

    for (int c = grp; c * 8 < M; c += GROUPS) {
        const int local0 = c * 8 + wave * 2;
        int cells[2]; bool live[2], validv[2];
        float wxv[2], wyv[2];
        v4f a[2], b[2], cc[2], d[2];
#pragma unroll
        for (int k = 0; k < 2; ++k) {
            const int local = local0 + k;
            live[k] = (local < M);
            const int g = gbase + min(local, M - 1);
            const int cell = list[g];
            cells[k] = cell;
            unsigned b00, b01, b10, b11;
            cell_geom(rois, cell, b00, b01, b10, b11, wyv[k], wxv[k], validv[k]);
            if (live[k]) {
                a[k]  = *(const v4f*)(x + b00 + c4);
                b[k]  = *(const v4f*)(x + b01 + c4);
                cc[k] = *(const v4f*)(x + b10 + c4);
                d[k]  = *(const v4f*)(x + b11 + c4);
            }
        }
#pragma unroll
        for (int k = 0; k < 2; ++k) {
            if (!live[k]) continue;
            const float wx = wxv[k], wy = wyv[k];
            const v4f top = a[k]  * (1.0f - wx) + b[k] * wx;
            const v4f bot = cc[k] * (1.0f - wx) + d[k] * wx;
            v4f res = top * (1.0f - wy) + bot * wy;
            if (!validv[k]) res = (v4f)0.0f;
            v4f* o = (v4f*)(out + (unsigned)cells[k] * C + c4);
            __builtin_nontemporal_store(res, o);
        }
    }
}

// Fallback (ws too small): direct kernel.
__global__ __launch_bounds__(256) void roi_pool_plain(
    const float* __restrict__ x, const float* __restrict__ rois,
    float* __restrict__ out)
{
    const int wave = threadIdx.x >> 6;
    const int lane = threadIdx.x & 63;
    const int cell0 = (blockIdx.x * 4 + wave) * 2;
    const unsigned c4 = (unsigned)lane * 4u;

    v4f a[2], b[2], c[2], d[2];
    float wxv[2], wyv[2]; bool validv[2];
#pragma unroll
    for (int k = 0; k < 2; ++k) {
        unsigned b00, b01, b10, b11;
        cell_geom(rois, cell0 + k, b00, b01, b10, b11, wyv[k], wxv[k], validv[k]);
        a[k] = *(const v4f*)(x + b00 + c4);
        b[k] = *(const v4f*)(x + b01 + c4);
        c[k] = *(const v4f*)(x + b10 + c4);
        d[k] = *(const v4f*)(x + b11 + c4);
    }
#pragma unroll
    for (int k = 0; k < 2; ++k) {
        const float wx = wxv[k], wy = wyv[k];
        const v4f top = a[k] * (1.0f - wx) + b[k] * wx;
        const v4f bot = c[k] * (1.0f - wx) + d[k] * wx;
        v4f res = top * (1.0f - wy) + bot * wy;
        if (!validv[k]) res = (v4f)0.0f;
        v4f* o = (v4f*)(out + (unsigned)(cell0 + k) * C + c4);
        __builtin_nontemporal_store(res, o);
    }
}

extern "C" void kernel_launch(void* const* d_in, const int* in_sizes, int n_in,
                              void* d_out, int out_size, void* d_ws, size_t ws_size,
                              hipStream_t stream)
{
    const float* x    = (const float*)d_in[0];
    const float* rois = (const float*)d_in[1];
    float* out = (float*)d_out;

    if (ws_size >= WS_INTS * sizeof(int)) {
        int* cnt  = (int*)d_ws;
        int* head = cnt + WS_CNT;
        int* P    = head + WS_CNT;
        int* list = P + (NB + 1);
        zero_counts<<<32, 256, 0, stream>>>(cnt);
        hist_cells<<<BIN_BLOCKS, 256, 0, stream>>>(rois, cnt);
        prefix_sum<<<1, NB, 0, stream>>>(cnt, P);
        scatter_cells<<<BIN_BLOCKS, 256, 0, stream>>>(rois, P, head, list);
        roi_pool_flat<<<P2_BLOCKS, 256, 0, stream>>>(x, rois, out, list);
    } else {
        roi_pool_plain<<<NCELL / 8, 256, 0, stream>>>(x, rois, out);
    }
}

// Round 12
// 60.743 us; speedup vs baseline: 1.5322x; 1.2023x over previous
//
#include <hip/hip_runtime.h>

// RoiPooling (crop_and_resize, bilinear): x (1,128,128,256) f32 NHWC,
// rois (4000,4) f32 [y1,x1,y2,x2] in [0,1] -> out (4000,7,7,256) f32.
//
// R12: sort (r,iy) PAIRS by y0 (not cells). All 7 cells of an output row
// share y0/y1i/wy, so: sort is 7x smaller (28000 items, <=1 per thread in
// scatter -> no scratch arrays), and the pool does 7 cells per wave per
// pair: roi+y-math once, 28 independent gathers (deep MLP), 7KB contiguous
// NT write. Ordering (y0-sorted) identical to R9's best-known locality.

typedef float v4f __attribute__((ext_vector_type(4)));

constexpr int H = 128, W = 128, C = 256;
constexpr int PH = 7, PW = 7;
constexpr int NROI = 4000;
constexpr int NPAIR = NROI * PH;                 // 28000
constexpr int RBUCK = 128;                       // one bucket per y0 row
constexpr int CSTRIDE = 16;                      // ints; 64B per counter
constexpr int BIN_BLOCKS = (NPAIR + 255) / 256;  // 110
constexpr int NXCD = 8;
constexpr int M = NPAIR / NXCD;                  // 3500 pairs per XCD
constexpr int GROUPS = 256;                      // blocks per XCD
constexpr int P2_BLOCKS = NXCD * GROUPS;         // 2048
constexpr size_t WS_CNT  = (size_t)RBUCK * CSTRIDE;
constexpr size_t WS_INTS = 2 * WS_CNT + (RBUCK + 1) + NPAIR;

__global__ __launch_bounds__(256) void zero_counts(int* p) {
    const int n = (int)(2 * WS_CNT);
    for (int j = threadIdx.x; j < n; j += 256) p[j] = 0;
}

__device__ __forceinline__ int pair_ybucket(const float* __restrict__ rois, int pr) {
    const int r  = pr / PH;
    const int iy = pr - r * PH;
    const float y1 = rois[r * 4 + 0];
    const float y2 = rois[r * 4 + 2];
    const float ys = y1 * (float)(H - 1) + (float)iy * ((y2 - y1) * (float)(H - 1) / (float)(PH - 1));
    int y0 = (int)floorf(ys);
    return min(max(y0, 0), H - 1);
}

__global__ __launch_bounds__(256) void hist_pairs(const float* __restrict__ rois,
                                                  int* __restrict__ cnt)
{
    __shared__ int lh[RBUCK];
    if (threadIdx.x < RBUCK) lh[threadIdx.x] = 0;
    __syncthreads();
    const int pr = blockIdx.x * 256 + threadIdx.x;
    if (pr < NPAIR) atomicAdd(&lh[pair_ybucket(rois, pr)], 1);
    __syncthreads();
    if (threadIdx.x < RBUCK) {
        const int n = lh[threadIdx.x];
        if (n) atomicAdd(&cnt[threadIdx.x * CSTRIDE], n);
    }
}

__global__ __launch_bounds__(128) void prefix_sum(const int* __restrict__ cnt,
                                                  int* __restrict__ P)
{
    __shared__ int s[RBUCK];
    const int t = threadIdx.x;
    s[t] = cnt[t * CSTRIDE];
    __syncthreads();
    for (int off = 1; off < RBUCK; off <<= 1) {
        const int v = (t >= off) ? s[t - off] : 0;
        __syncthreads();
        s[t] += v;
        __syncthreads();
    }
    P[t + 1] = s[t];
    if (t == 0) P[0] = 0;
}

__global__ __launch_bounds__(256) void scatter_pairs(const float* __restrict__ rois,
                                                     const int* __restrict__ P,
                                                     int* __restrict__ head,
                                                     int* __restrict__ list)
{
    __shared__ int lcnt[RBUCK];
    __shared__ int gbase[RBUCK];
    if (threadIdx.x < RBUCK) lcnt[threadIdx.x] = 0;
    __syncthreads();
    const int pr = blockIdx.x * 256 + threadIdx.x;
    const bool active = pr < NPAIR;
    int b = 0, rank = 0;
    if (active) {
        b = pair_ybucket(rois, pr);
        rank = atomicAdd(&lcnt[b], 1);
    }
    __syncthreads();
    if (threadIdx.x < RBUCK) {
        const int n = lcnt[threadIdx.x];
        gbase[threadIdx.x] = n ? P[threadIdx.x] + atomicAdd(&head[threadIdx.x * CSTRIDE], n) : 0;
    }
    __syncthreads();
    if (active) {
        const int r  = pr / PH;
        const int iy = pr - r * PH;
        list[gbase[b] + rank] = (r << 3) | iy;   // packed
    }
}

__global__ __launch_bounds__(256) void roi_pool_pairs(
    const float* __restrict__ x, const float* __restrict__ rois,
    float* __restrict__ out, const int* __restrict__ list)
{
    const int xcd = blockIdx.x & (NXCD - 1);   // heuristic: == XCD id
    const int grp = blockIdx.x >> 3;
    const int wave = threadIdx.x >> 6;
    const int lane = threadIdx.x & 63;
    const unsigned c4 = (unsigned)lane * 4u;
    const int base = xcd * M;

    for (int i = grp * 4 + wave; i < M; i += GROUPS * 4) {
        const int packed = list[base + i];
        const int r  = packed >> 3;
        const int iy = packed & 7;

        const float y1 = rois[r * 4 + 0];
        const float x1 = rois[r * 4 + 1];
        const float y2 = rois[r * 4 + 2];
        const float x2 = rois[r * 4 + 3];

        // Match reference order exactly.
        const float ys = y1 * (float)(H - 1) + (float)iy * ((y2 - y1) * (float)(H - 1) / (float)(PH - 1));
        const float y0f = floorf(ys);
        const float wy = ys - y0f;
        int y0  = (int)y0f; y0  = min(max(y0, 0), H - 1);
        int y1i = min(y0 + 1, H - 1);
        const bool vy = (ys >= 0.0f) & (ys <= (float)(H - 1));

        const float* __restrict__ row0 = x + (unsigned)y0  * (W * C);
        const float* __restrict__ row1 = x + (unsigned)y1i * (W * C);
        float* __restrict__ obase = out + (unsigned)(r * 49 + iy * 7) * C;

#pragma unroll
        for (int ix = 0; ix < PW; ++ix) {
            const float xs = x1 * (float)(W - 1) + (float)ix * ((x2 - x1) * (float)(W - 1) / (float)(PW - 1));
            const float x0f = floorf(xs);
            const float wx = xs - x0f;
            int x0  = (int)x0f; x0  = min(max(x0, 0), W - 1);
            int x1c = min(x0 + 1, W - 1);
            const bool v = vy & (xs >= 0.0f) & (xs <= (float)(W - 1));

            const v4f a = *(const v4f*)(row0 + (unsigned)x0  * C + c4);
            const v4f b = *(const v4f*)(row0 + (unsigned)x1c * C + c4);
            const v4f c = *(const v4f*)(row1 + (unsigned)x0  * C + c4);
            const v4f d = *(const v4f*)(row1 + (unsigned)x1c * C + c4);

            const v4f top = a * (1.0f - wx) + b * wx;
            const v4f bot = c * (1.0f - wx) + d * wx;
            v4f res = top * (1.0f - wy) + bot * wy;
            if (!v) res = (v4f)0.0f;
            __builtin_nontemporal_store(res, (v4f*)(obase + (unsigned)ix * C + c4));
        }
    }
}

// Fallback (ws too small): direct kernel over cells.
__global__ __launch_bounds__(256) void roi_pool_plain(
    const float* __restrict__ x, const float* __restrict__ rois,
    float* __restrict__ out)
{
    const int wave = threadIdx.x >> 6;
    const int lane = threadIdx.x & 63;
    const int pr = blockIdx.x * 4 + wave;      // one pair per wave
    if (pr >= NPAIR) return;
    const int r  = pr / PH;
    const int iy = pr - r * PH;
    const unsigned c4 = (unsigned)lane * 4u;

    const float y1 = rois[r * 4 + 0];
    const float x1 = rois[r * 4 + 1];
    const float y2 = rois[r * 4 + 2];
    const float x2 = rois[r * 4 + 3];

    const float ys = y1 * (float)(H - 1) + (float)iy * ((y2 - y1) * (float)(H - 1) / (float)(PH - 1));
    const float y0f = floorf(ys);
    const float wy = ys - y0f;
    int y0  = (int)y0f; y0  = min(max(y0, 0), H - 1);
    int y1i = min(y0 + 1, H - 1);
    const bool vy = (ys >= 0.0f) & (ys <= (float)(H - 1));

    const float* __restrict__ row0 = x + (unsigned)y0  * (W * C);
    const float* __restrict__ row1 = x + (unsigned)y1i * (W * C);
    float* __restrict__ obase = out + (unsigned)(r * 49 + iy * 7) * C;

#pragma unroll
    for (int ix = 0; ix < PW; ++ix) {
        const float xs = x1 * (float)(W - 1) + (float)ix * ((x2 - x1) * (float)(W - 1) / (float)(PW - 1));
        const float x0f = floorf(xs);
        const float wx = xs - x0f;
        int x0  = (int)x0f; x0  = min(max(x0, 0), W - 1);
        int x1c = min(x0 + 1, W - 1);
        const bool v = vy & (xs >= 0.0f) & (xs <= (float)(W - 1));

        const v4f a = *(const v4f*)(row0 + (unsigned)x0  * C + c4);
        const v4f b = *(const v4f*)(row0 + (unsigned)x1c * C + c4);
        const v4f c = *(const v4f*)(row1 + (unsigned)x0  * C + c4);
        const v4f d = *(const v4f*)(row1 + (unsigned)x1c * C + c4);

        const v4f top = a * (1.0f - wx) + b * wx;
        const v4f bot = c * (1.0f - wx) + d * wx;
        v4f res = top * (1.0f - wy) + bot * wy;
        if (!v) res = (v4f)0.0f;
        __builtin_nontemporal_store(res, (v4f*)(obase + (unsigned)ix * C + c4));
    }
}

extern "C" void kernel_launch(void* const* d_in, const int* in_sizes, int n_in,
                              void* d_out, int out_size, void* d_ws, size_t ws_size,
                              hipStream_t stream)
{
    const float* x    = (const float*)d_in[0];
    const float* rois = (const float*)d_in[1];
    float* out = (float*)d_out;

    if (ws_size >= WS_INTS * sizeof(int)) {
        int* cnt  = (int*)d_ws;
        int* head = cnt + WS_CNT;
        int* P    = head + WS_CNT;
        int* list = P + (RBUCK + 1);
        zero_counts<<<1, 256, 0, stream>>>(cnt);
        hist_pairs<<<BIN_BLOCKS, 256, 0, stream>>>(rois, cnt);
        prefix_sum<<<1, 128, 0, stream>>>(cnt, P);
        scatter_pairs<<<BIN_BLOCKS, 256, 0, stream>>>(rois, P, head, list);
        roi_pool_pairs<<<P2_BLOCKS, 256, 0, stream>>>(x, rois, out, list);
    } else {
        roi_pool_plain<<<(NPAIR + 3) / 4, 256, 0, stream>>>(x, rois, out);
    }
}